// Round 2
// baseline (407.367 us; speedup 1.0000x reference)
//
#include <hip/hip_runtime.h>

// ---------------------------------------------------------------------------
// CodecTransformerLayer on MI355X (gfx950).  Dtype-self-detecting: a sniff
// kernel decides at runtime whether device buffers are bf16 or fp32 (the
// reference declares fp32; the harness flavor may be bf16).  All internal
// compute is bf16 MFMA.
// B=2 S=2048 D=1024 H=16 KVH=8 hd=64 HIDDEN=4096 WINDOW=512
// ---------------------------------------------------------------------------

typedef __bf16 bf16;
typedef __attribute__((ext_vector_type(8))) __bf16 bf16x8;
typedef __attribute__((ext_vector_type(4))) float f32x4;
typedef __attribute__((ext_vector_type(4))) short s16x4;

#define MFMA16(a, b, c) __builtin_amdgcn_mfma_f32_16x16x32_bf16(a, b, c, 0, 0, 0)

__device__ __forceinline__ void gload_lds16(const bf16* g, bf16* l) {
    __builtin_amdgcn_global_load_lds(
        (const __attribute__((address_space(1))) unsigned int*)g,
        (__attribute__((address_space(3))) unsigned int*)l, 16, 0, 0);
}

// ---------------------------------------------------------------------------
// Dtype sniff: read first 4096 halfwords of x as bf16.  Real bf16 activations
// (N(0,1)) have exponent <= 129; fp32 mantissa halves decode with ~uniform
// exponent -> certain detection over 4096 samples.  flag=1 means fp32 inputs.
// ---------------------------------------------------------------------------
__global__ void sniff_kernel(const unsigned short* __restrict__ x, int* __restrict__ flag) {
    __shared__ int s;
    if (threadIdx.x == 0) s = 0;
    __syncthreads();
    int bad = 0;
#pragma unroll
    for (int i = 0; i < 16; ++i) {
        const unsigned short u = x[threadIdx.x * 16 + i];
        const int e = (u >> 7) & 0xFF;
        if (e >= 135) bad = 1;       // |v| >= 128 or NaN/Inf: impossible for real data
    }
    if (bad) atomicOr(&s, 1);
    __syncthreads();
    if (threadIdx.x == 0) flag[0] = s;
}

// ---------------------------------------------------------------------------
// fp32 -> bf16 weight conversion (only runs when flag==1).  All 7 weight
// matrices concatenated into one contiguous ws region.
// seg map (elements): wq[0) wk[1048576) wv[1572864) wo[2097152) w1[3145728)
//                     w3[7340032) w2[11534336) end 15728640
// ---------------------------------------------------------------------------
__global__ void convert_all_kernel(const float* __restrict__ wq, const float* __restrict__ wk,
                                   const float* __restrict__ wv, const float* __restrict__ wo,
                                   const float* __restrict__ w1, const float* __restrict__ w3,
                                   const float* __restrict__ w2, bf16* __restrict__ dst,
                                   const int* __restrict__ flag) {
    if (flag[0] == 0) return;
    const long e = ((long)blockIdx.x * 256 + threadIdx.x) * 4;
    const float* src; long off;
    if      (e < 1048576)  { src = wq; off = 0; }
    else if (e < 1572864)  { src = wk; off = 1048576; }
    else if (e < 2097152)  { src = wv; off = 1572864; }
    else if (e < 3145728)  { src = wo; off = 2097152; }
    else if (e < 7340032)  { src = w1; off = 3145728; }
    else if (e < 11534336) { src = w3; off = 7340032; }
    else                   { src = w2; off = 11534336; }
    const f32x4 v = *(const f32x4*)(src + (e - off));
    bf16 tmp[4];
#pragma unroll
    for (int j = 0; j < 4; ++j) tmp[j] = (bf16)v[j];
    *(s16x4*)(dst + e) = *(s16x4*)tmp;
}

// ---------------------------------------------------------------------------
// LayerNorm over last dim W (1024 or 512), one 128-thread block per row.
// in_flv/w_flv: pointer is flavor-typed (fp32 when flag==1).  out is bf16.
// ---------------------------------------------------------------------------
__global__ void ln_kernel(const void* __restrict__ in, const void* __restrict__ w,
                          bf16* __restrict__ out, int W, float eps,
                          const int* __restrict__ flag, int in_flv, int w_flv) {
    const int row = blockIdx.x, t = threadIdx.x;
    const int nch = W >> 3;
    const bool act = t < nch;
    const bool f32 = flag[0] != 0;
    float v[8];
    float s = 0.f, s2 = 0.f;
    if (act) {
        if (in_flv && f32) {
            const float* rp = (const float*)in + (size_t)row * W + t * 8;
            const f32x4 a = *(const f32x4*)rp, b = *(const f32x4*)(rp + 4);
#pragma unroll
            for (int j = 0; j < 4; ++j) { v[j] = a[j]; v[4 + j] = b[j]; }
        } else {
            const bf16x8 xv = *(const bf16x8*)((const bf16*)in + (size_t)row * W + t * 8);
#pragma unroll
            for (int j = 0; j < 8; ++j) v[j] = (float)xv[j];
        }
#pragma unroll
        for (int j = 0; j < 8; ++j) { s += v[j]; s2 += v[j] * v[j]; }
    }
#pragma unroll
    for (int off = 32; off; off >>= 1) { s += __shfl_xor(s, off); s2 += __shfl_xor(s2, off); }
    __shared__ float red[4];
    if ((t & 63) == 0) { red[(t >> 6) * 2] = s; red[(t >> 6) * 2 + 1] = s2; }
    __syncthreads();
    const float fs = red[0] + red[2], fs2 = red[1] + red[3];
    const float inw = 1.f / (float)W;
    const float mean = fs * inw;
    const float var = fs2 * inw - mean * mean;
    const float rstd = rsqrtf(var + eps);
    if (act) {
        float wv8[8];
        if (w_flv && f32) {
            const float* wp = (const float*)w + t * 8;
            const f32x4 a = *(const f32x4*)wp, b = *(const f32x4*)(wp + 4);
#pragma unroll
            for (int j = 0; j < 4; ++j) { wv8[j] = a[j]; wv8[4 + j] = b[j]; }
        } else {
            const bf16x8 ww = *(const bf16x8*)((const bf16*)w + t * 8);
#pragma unroll
            for (int j = 0; j < 8; ++j) wv8[j] = (float)ww[j];
        }
        bf16x8 ov;
#pragma unroll
        for (int j = 0; j < 8; ++j) ov[j] = (bf16)((v[j] - mean) * rstd * wv8[j]);
        *(bf16x8*)(out + (size_t)row * W + t * 8) = ov;
    }
}

// ---------------------------------------------------------------------------
// GEMM  C[M,N] = A[M,K] * B[N,K]^T   (m97 structure: 128x128 tile, BK=32,
// 4 waves, global_load_lds width 16, mfma 16x16x32 bf16).  B pointer selected
// by flag (orig bf16 vs converted).  Epilogues:
//   0: C = acc                    2: transposed V store Vt[b][kvh][d][s]
//   1: C = res + acc*scale[col]   3: C = silu(res)*acc
// ---------------------------------------------------------------------------
template <int EPI>
__global__ __launch_bounds__(256, 2)
void gemm_bt(const bf16* __restrict__ A, const bf16* __restrict__ Borig,
             const bf16* __restrict__ Bconv, void* __restrict__ Cout,
             const void* __restrict__ res, const void* __restrict__ scale,
             int M, int N, int K, const int* __restrict__ flag,
             int res_flv, int out_flv) {
    const bool f32 = flag[0] != 0;
    const bf16* B = f32 ? Bconv : Borig;
    __shared__ bf16 As[128 * 32];
    __shared__ bf16 Bs[128 * 32];
    const int t = threadIdx.x;
    const int wv = t >> 6, ln = t & 63;
    const int qr = ln & 15, g = ln >> 4;
    const int row0 = blockIdx.y * 128, col0 = blockIdx.x * 128;
    const int wrow = (wv >> 1) * 64, wcol = (wv & 1) * 64;

    f32x4 acc[4][4] = {};

    const bf16* a0 = A + (size_t)(row0 + (t >> 2)) * K + (t & 3) * 8;
    const bf16* a1 = A + (size_t)(row0 + 64 + (t >> 2)) * K + (t & 3) * 8;
    const bf16* b0 = B + (size_t)(col0 + (t >> 2)) * K + (t & 3) * 8;
    const bf16* b1 = B + (size_t)(col0 + 64 + (t >> 2)) * K + (t & 3) * 8;
    bf16* lA0 = As + wv * 512;
    bf16* lA1 = As + 2048 + wv * 512;
    bf16* lB0 = Bs + wv * 512;
    bf16* lB1 = Bs + 2048 + wv * 512;

    for (int k0 = 0; k0 < K; k0 += 32) {
        gload_lds16(a0 + k0, lA0);
        gload_lds16(a1 + k0, lA1);
        gload_lds16(b0 + k0, lB0);
        gload_lds16(b1 + k0, lB1);
        __syncthreads();
        bf16x8 af[4], bfr[4];
#pragma unroll
        for (int i = 0; i < 4; ++i) {
            af[i]  = *(const bf16x8*)&As[(wrow + i * 16 + qr) * 32 + g * 8];
            bfr[i] = *(const bf16x8*)&Bs[(wcol + i * 16 + qr) * 32 + g * 8];
        }
#pragma unroll
        for (int i = 0; i < 4; ++i)
#pragma unroll
            for (int j = 0; j < 4; ++j)
                acc[i][j] = MFMA16(af[i], bfr[j], acc[i][j]);
        __syncthreads();
    }

#pragma unroll
    for (int i = 0; i < 4; ++i) {
#pragma unroll
        for (int j = 0; j < 4; ++j) {
            const int rr0 = row0 + wrow + i * 16 + g * 4;  // C/D: row=(l>>4)*4+r
            const int cc  = col0 + wcol + j * 16 + qr;     //      col=l&15
            if (EPI == 2) {
                const int bb = rr0 >> 11, s0 = rr0 & 2047;
                const int kvh = cc >> 6, d = cc & 63;
                bf16 tmp[4];
#pragma unroll
                for (int r = 0; r < 4; ++r) tmp[r] = (bf16)acc[i][j][r];
                *(s16x4*)((bf16*)Cout + (((size_t)bb * 8 + kvh) * 64 + d) * 2048 + s0) = *(s16x4*)tmp;
            } else {
                float scv = 0.f;
                if (EPI == 1)
                    scv = f32 ? ((const float*)scale)[cc] : (float)((const bf16*)scale)[cc];
#pragma unroll
                for (int r = 0; r < 4; ++r) {
                    const size_t idx = (size_t)(rr0 + r) * N + cc;
                    float vv = acc[i][j][r];
                    if (EPI == 1) {
                        const float rv = (res_flv && f32) ? ((const float*)res)[idx]
                                                          : (float)((const bf16*)res)[idx];
                        vv = rv + vv * scv;
                    }
                    if (EPI == 3) {
                        const float uv = (float)((const bf16*)res)[idx];
                        vv = uv / (1.f + __expf(-uv)) * vv;
                    }
                    if (out_flv && f32) ((float*)Cout)[idx] = vv;
                    else                ((bf16*)Cout)[idx] = (bf16)vv;
                }
            }
        }
    }
}

// ---------------------------------------------------------------------------
// Windowed-ALiBi GQA flash attention (key in [q, q+512]).  Grid (S/64, H, B),
// 4 independent waves/block, wave = 16 queries.  Swapped QK^T (S^T=mfma(K,Q))
// so softmax state is lane-local; PV B-operand (P^T) built via 16 __shfl.
// All operands bf16 internal; no LDS.
// ---------------------------------------------------------------------------
__global__ __launch_bounds__(256)
void attn_kernel(const bf16* __restrict__ qn, const bf16* __restrict__ kn,
                 const bf16* __restrict__ vt, bf16* __restrict__ aout) {
    const int t = threadIdx.x, wv = t >> 6, ln = t & 63;
    const int qr = ln & 15, g = ln >> 4;
    const int h = blockIdx.y, b = blockIdx.z, kvh = h >> 1;
    const int q0w = blockIdx.x * 64 + wv * 16;
    const int qa = q0w + qr;
    const float slope = exp2f(-0.5f * (float)(h + 1));

    const bf16* qrow = qn + ((size_t)(b * 2048 + qa)) * 1024 + h * 64;
    const bf16x8 qb0 = *(const bf16x8*)(qrow + g * 8);
    const bf16x8 qb1 = *(const bf16x8*)(qrow + 32 + g * 8);

    const bf16* kbase = kn + (size_t)b * 2048 * 512 + kvh * 64;
    const bf16* vbase = vt + ((size_t)(b * 8 + kvh) * 64) * 2048;

    f32x4 o[4] = {};
    float mrun = -1e29f, lsum = 0.f;

    for (int kt = q0w; kt < q0w + 528; kt += 32) {
        f32x4 sc[2] = {f32x4{0, 0, 0, 0}, f32x4{0, 0, 0, 0}};
#pragma unroll
        for (int kf = 0; kf < 2; ++kf) {
            int krow = kt + kf * 16 + qr;
            krow = krow > 2047 ? 2047 : krow;
            const bf16* kr = kbase + (size_t)krow * 512;
            sc[kf] = MFMA16(*(const bf16x8*)(kr + g * 8),      qb0, sc[kf]);
            sc[kf] = MFMA16(*(const bf16x8*)(kr + 32 + g * 8), qb1, sc[kf]);
        }
        float s[2][4], p[2][4];
        float tmax = -1e30f;
#pragma unroll
        for (int kf = 0; kf < 2; ++kf)
#pragma unroll
            for (int r = 0; r < 4; ++r) {
                const int key = kt + kf * 16 + g * 4 + r;
                const int dist = key - qa;
                const bool valid = (dist >= 0) && (dist <= 512) && (key < 2048);
                const float sv = valid ? sc[kf][r] * 0.125f - slope * (float)dist : -1e30f;
                s[kf][r] = sv;
                tmax = fmaxf(tmax, sv);
            }
        tmax = fmaxf(tmax, __shfl_xor(tmax, 16));
        tmax = fmaxf(tmax, __shfl_xor(tmax, 32));
        const float mnew = fmaxf(mrun, tmax);
        const float alpha = __expf(mrun - mnew);
        mrun = mnew;
        float ps = 0.f;
#pragma unroll
        for (int kf = 0; kf < 2; ++kf)
#pragma unroll
            for (int r = 0; r < 4; ++r) { p[kf][r] = __expf(s[kf][r] - mnew); ps += p[kf][r]; }
        lsum = lsum * alpha + ps;
#pragma unroll
        for (int fd = 0; fd < 4; ++fd) o[fd] *= alpha;

        bf16x8 pb;
#pragma unroll
        for (int j = 0; j < 8; ++j) {
            const int srcl = (((2 * g + (j >> 2)) & 3) << 4) | qr;
            const float v0 = __shfl(p[0][j & 3], srcl);
            const float v1 = __shfl(p[1][j & 3], srcl);
            pb[j] = (bf16)((g & 2) ? v1 : v0);
        }
#pragma unroll
        for (int fd = 0; fd < 4; ++fd) {
            int kbv = kt + g * 8;
            kbv = kbv > 2040 ? 2040 : kbv;
            const bf16x8 va = *(const bf16x8*)(vbase + (size_t)(fd * 16 + qr) * 2048 + kbv);
            o[fd] = MFMA16(va, pb, o[fd]);
        }
    }
    float lt = lsum + __shfl_xor(lsum, 16);
    lt += __shfl_xor(lt, 32);
    lt = fmaxf(lt, 1e-30f);
    const float inv = 1.f / lt;
    bf16* orow = aout + ((size_t)(b * 2048 + qa)) * 1024 + h * 64;
#pragma unroll
    for (int fd = 0; fd < 4; ++fd) {
        bf16 tmp[4];
#pragma unroll
        for (int r = 0; r < 4; ++r) tmp[r] = (bf16)(o[fd][r] * inv);
        *(s16x4*)(orow + fd * 16 + g * 4) = *(s16x4*)tmp;
    }
}

// ---------------------------------------------------------------------------
extern "C" void kernel_launch(void* const* d_in, const int* in_sizes, int n_in,
                              void* d_out, int out_size, void* d_ws, size_t ws_size,
                              hipStream_t stream) {
    int* flag = (int*)d_ws;
    bf16* base = (bf16*)d_ws + 64;
    bf16* h    = base;                // 4096*1024  (reused as h2)
    bf16* q    = h + 4194304;         // 4096*1024  (reused as x1 after attn)
    bf16* kbuf = q + 4194304;         // 4096*512
    bf16* vtb  = kbuf + 2097152;      // 2*8*64*2048
    bf16* aout = vtb + 2097152;       // 4096*1024
    bf16* u    = aout + 4194304;      // 4096*4096  (reused as act)
    bf16* wcv  = u + 16777216;        // 15728640 converted weights
    const bool canconv = ws_size >= (size_t)(64 + 49283072) * 2;

    bf16* wqc = canconv ? wcv            : (bf16*)d_in[1];
    bf16* wkc = canconv ? wcv + 1048576  : (bf16*)d_in[2];
    bf16* wvc = canconv ? wcv + 1572864  : (bf16*)d_in[3];
    bf16* woc = canconv ? wcv + 2097152  : (bf16*)d_in[4];
    bf16* w1c = canconv ? wcv + 3145728  : (bf16*)d_in[9];
    bf16* w3c = canconv ? wcv + 7340032  : (bf16*)d_in[11];
    bf16* w2c = canconv ? wcv + 11534336 : (bf16*)d_in[10];

    const dim3 blk(256);
    sniff_kernel<<<1, 256, 0, stream>>>((const unsigned short*)d_in[0], flag);
    if (canconv)
        convert_all_kernel<<<15360, 256, 0, stream>>>(
            (const float*)d_in[1], (const float*)d_in[2], (const float*)d_in[3],
            (const float*)d_in[4], (const float*)d_in[9], (const float*)d_in[11],
            (const float*)d_in[10], wcv, flag);

    ln_kernel<<<4096, 128, 0, stream>>>(d_in[0], d_in[7], h, 1024, 1e-5f, flag, 1, 1);
    gemm_bt<0><<<dim3(8, 32),  blk, 0, stream>>>(h, (const bf16*)d_in[1], wqc, q,    nullptr, nullptr, 4096, 1024, 1024, flag, 0, 0);
    gemm_bt<0><<<dim3(4, 32),  blk, 0, stream>>>(h, (const bf16*)d_in[2], wkc, kbuf, nullptr, nullptr, 4096,  512, 1024, flag, 0, 0);
    gemm_bt<2><<<dim3(4, 32),  blk, 0, stream>>>(h, (const bf16*)d_in[3], wvc, vtb,  nullptr, nullptr, 4096,  512, 1024, flag, 0, 0);
    ln_kernel<<<4096, 128, 0, stream>>>(q, d_in[5], q, 1024, 1e-6f, flag, 0, 1);
    ln_kernel<<<4096, 128, 0, stream>>>(kbuf, d_in[6], kbuf, 512, 1e-6f, flag, 0, 1);
    attn_kernel<<<dim3(32, 16, 2), blk, 0, stream>>>(q, kbuf, vtb, aout);
    gemm_bt<1><<<dim3(8, 32),  blk, 0, stream>>>(aout, (const bf16*)d_in[4], woc, q, d_in[0], d_in[12], 4096, 1024, 1024, flag, 1, 0);
    ln_kernel<<<4096, 128, 0, stream>>>(q, d_in[8], h, 1024, 1e-5f, flag, 0, 1);
    gemm_bt<0><<<dim3(32, 32), blk, 0, stream>>>(h, (const bf16*)d_in[9],  w1c, u, nullptr, nullptr, 4096, 4096, 1024, flag, 0, 0);
    gemm_bt<3><<<dim3(32, 32), blk, 0, stream>>>(h, (const bf16*)d_in[11], w3c, u, u,       nullptr, 4096, 4096, 1024, flag, 0, 0);
    gemm_bt<1><<<dim3(8, 32),  blk, 0, stream>>>(u, (const bf16*)d_in[10], w2c, d_out, q,   d_in[13], 4096, 1024, 4096, flag, 0, 1);
}

// Round 3
// 308.784 us; speedup vs baseline: 1.3193x; 1.3193x over previous
//
#include <hip/hip_runtime.h>

// ---------------------------------------------------------------------------
// CodecTransformerLayer on MI355X (gfx950).  fp32 inputs (sniff-confirmed),
// bf16 internal compute.  Round 3: all GEMMs -> 512-thread 8-wave 128x128
// tile with 3-buffer counted-vmcnt pipeline (T4); QKV fused into one GEMM.
// B=2 S=2048 D=1024 H=16 KVH=8 hd=64 HIDDEN=4096 WINDOW=512
// ---------------------------------------------------------------------------

typedef __bf16 bf16;
typedef __attribute__((ext_vector_type(8))) __bf16 bf16x8;
typedef __attribute__((ext_vector_type(4))) float f32x4;
typedef __attribute__((ext_vector_type(4))) short s16x4;

#define MFMA16(a, b, c) __builtin_amdgcn_mfma_f32_16x16x32_bf16(a, b, c, 0, 0, 0)

__device__ __forceinline__ void gload_lds16(const bf16* g, bf16* l) {
    __builtin_amdgcn_global_load_lds(
        (const __attribute__((address_space(1))) unsigned int*)g,
        (__attribute__((address_space(3))) unsigned int*)l, 16, 0, 0);
}

// ---------------------------------------------------------------------------
// Dtype sniff: flag=1 means fp32 inputs (bf16 reinterpretation would show
// impossible exponents).
// ---------------------------------------------------------------------------
__global__ void sniff_kernel(const unsigned short* __restrict__ x, int* __restrict__ flag) {
    __shared__ int s;
    if (threadIdx.x == 0) s = 0;
    __syncthreads();
    int bad = 0;
#pragma unroll
    for (int i = 0; i < 16; ++i) {
        const unsigned short u = x[threadIdx.x * 16 + i];
        const int e = (u >> 7) & 0xFF;
        if (e >= 135) bad = 1;
    }
    if (bad) atomicOr(&s, 1);
    __syncthreads();
    if (threadIdx.x == 0) flag[0] = s;
}

// ---------------------------------------------------------------------------
// Weight gather -> contiguous bf16 (convert when fp32, copy when bf16).
// seg map (elements): wq[0) wk[1048576) wv[1572864) wo[2097152) w1[3145728)
//                     w3[7340032) w2[11534336) end 15728640
// ---------------------------------------------------------------------------
__global__ void convert_all_kernel(const void* __restrict__ wq, const void* __restrict__ wk,
                                   const void* __restrict__ wv, const void* __restrict__ wo,
                                   const void* __restrict__ w1, const void* __restrict__ w3,
                                   const void* __restrict__ w2, bf16* __restrict__ dst,
                                   const int* __restrict__ flag) {
    const long e = ((long)blockIdx.x * 256 + threadIdx.x) * 4;
    const void* src; long off;
    if      (e < 1048576)  { src = wq; off = 0; }
    else if (e < 1572864)  { src = wk; off = 1048576; }
    else if (e < 2097152)  { src = wv; off = 1572864; }
    else if (e < 3145728)  { src = wo; off = 2097152; }
    else if (e < 7340032)  { src = w1; off = 3145728; }
    else if (e < 11534336) { src = w3; off = 7340032; }
    else                   { src = w2; off = 11534336; }
    if (flag[0] != 0) {
        const f32x4 v = *(const f32x4*)((const float*)src + (e - off));
        bf16 tmp[4];
#pragma unroll
        for (int j = 0; j < 4; ++j) tmp[j] = (bf16)v[j];
        *(s16x4*)(dst + e) = *(s16x4*)tmp;
    } else {
        *(s16x4*)(dst + e) = *(const s16x4*)((const short*)src + (e - off));
    }
}

// ---------------------------------------------------------------------------
// LayerNorm over last dim W (1024 or 512), one 128-thread block per row.
// ---------------------------------------------------------------------------
__global__ void ln_kernel(const void* __restrict__ in, const void* __restrict__ w,
                          bf16* __restrict__ out, int W, float eps,
                          const int* __restrict__ flag, int in_flv, int w_flv) {
    const int row = blockIdx.x, t = threadIdx.x;
    const int nch = W >> 3;
    const bool act = t < nch;
    const bool f32 = flag[0] != 0;
    float v[8];
    float s = 0.f, s2 = 0.f;
    if (act) {
        if (in_flv && f32) {
            const float* rp = (const float*)in + (size_t)row * W + t * 8;
            const f32x4 a = *(const f32x4*)rp, b = *(const f32x4*)(rp + 4);
#pragma unroll
            for (int j = 0; j < 4; ++j) { v[j] = a[j]; v[4 + j] = b[j]; }
        } else {
            const bf16x8 xv = *(const bf16x8*)((const bf16*)in + (size_t)row * W + t * 8);
#pragma unroll
            for (int j = 0; j < 8; ++j) v[j] = (float)xv[j];
        }
#pragma unroll
        for (int j = 0; j < 8; ++j) { s += v[j]; s2 += v[j] * v[j]; }
    }
#pragma unroll
    for (int off = 32; off; off >>= 1) { s += __shfl_xor(s, off); s2 += __shfl_xor(s2, off); }
    __shared__ float red[4];
    if ((t & 63) == 0) { red[(t >> 6) * 2] = s; red[(t >> 6) * 2 + 1] = s2; }
    __syncthreads();
    const float fs = red[0] + red[2], fs2 = red[1] + red[3];
    const float inw = 1.f / (float)W;
    const float mean = fs * inw;
    const float var = fs2 * inw - mean * mean;
    const float rstd = rsqrtf(var + eps);
    if (act) {
        float wv8[8];
        if (w_flv && f32) {
            const float* wp = (const float*)w + t * 8;
            const f32x4 a = *(const f32x4*)wp, b = *(const f32x4*)(wp + 4);
#pragma unroll
            for (int j = 0; j < 4; ++j) { wv8[j] = a[j]; wv8[4 + j] = b[j]; }
        } else {
            const bf16x8 ww = *(const bf16x8*)((const bf16*)w + t * 8);
#pragma unroll
            for (int j = 0; j < 8; ++j) wv8[j] = (float)ww[j];
        }
        bf16x8 ov;
#pragma unroll
        for (int j = 0; j < 8; ++j) ov[j] = (bf16)((v[j] - mean) * rstd * wv8[j]);
        *(bf16x8*)(out + (size_t)row * W + t * 8) = ov;
    }
}

// ---------------------------------------------------------------------------
// Pipelined GEMM  C[M,N] = A[M,K] * B[N,K]^T
// 128x128 tile, BK=32, 512 threads (8 waves as 2Mx4N: wave owns 64x32),
// 3 LDS buffers, counted vmcnt (steady state never drains to 0), raw
// s_barrier + sched_barrier(0) so the compiler cannot re-insert a drain.
// Ledger (per wave, 2 gload_lds per tile): prologue stages t0,t1 -> 4
// outstanding, vmcnt(2) waits t0.  Iter it: stage t_{it+2} into buf
// (it+2)%3 (freed at iter it-1's trailing barrier), compute t_it,
// vmcnt(2) retires t_{it+1} (oldest), barrier publishes.  Tail: vmcnt(0).
// Epilogues: 0 plain bf16; 1 res+acc*scale[col]; 3 silu(res)*acc;
//            4 fused QKV split (q | k | v-transposed).
// ---------------------------------------------------------------------------
template <int EPI>
__global__ __launch_bounds__(512, 4)
void gemm2(const bf16* __restrict__ A, const bf16* __restrict__ B,
           void* __restrict__ Cout, const void* __restrict__ res,
           const void* __restrict__ scale, int M, int N, int K,
           const int* __restrict__ flag, int res_flv, int out_flv) {
    __shared__ bf16 LDS[3 * 8192];      // per buf: A 4096 | B 4096  (48 KiB)
    const bool f32 = flag[0] != 0;
    const int t = threadIdx.x;
    const int wv = t >> 6, ln = t & 63;
    const int qr = ln & 15, g = ln >> 4;
    const int wr = wv >> 2, wc = wv & 3;          // wave grid 2(M) x 4(N)
    const int row0 = blockIdx.y * 128, col0 = blockIdx.x * 128;

    f32x4 acc[4][2] = {};

    // thread t stages chunk t: row = t>>2, k-off = (t&3)*8 of the 128x32 slab
    const bf16* aSrc = A + (size_t)(row0 + (t >> 2)) * K + (t & 3) * 8;
    const bf16* bSrc = B + (size_t)(col0 + (t >> 2)) * K + (t & 3) * 8;
    const int NIT = K >> 5;

#define STAGE(bi, k0)                                              \
    do {                                                           \
        bf16* lb = LDS + (bi) * 8192 + wv * 512;                   \
        gload_lds16(aSrc + (k0), lb);                              \
        gload_lds16(bSrc + (k0), lb + 4096);                       \
    } while (0)

    STAGE(0, 0);
    STAGE(1, 32);
    asm volatile("s_waitcnt vmcnt(2)" ::: "memory");
    __builtin_amdgcn_s_barrier();
    __builtin_amdgcn_sched_barrier(0);

    int cur = 0, sb = 2;
    for (int it = 0; it < NIT; ++it) {
        const bool more = (it + 2) < NIT;
        if (more) STAGE(sb, (it + 2) * 32);
        const bf16* bufA = LDS + cur * 8192;
        const bf16* bufB = bufA + 4096;
        bf16x8 af[4], bfr[2];
#pragma unroll
        for (int i = 0; i < 4; ++i)
            af[i] = *(const bf16x8*)&bufA[(wr * 64 + i * 16 + qr) * 32 + g * 8];
#pragma unroll
        for (int j = 0; j < 2; ++j)
            bfr[j] = *(const bf16x8*)&bufB[(wc * 32 + j * 16 + qr) * 32 + g * 8];
#pragma unroll
        for (int i = 0; i < 4; ++i)
#pragma unroll
            for (int j = 0; j < 2; ++j)
                acc[i][j] = MFMA16(af[i], bfr[j], acc[i][j]);
        if (more) asm volatile("s_waitcnt vmcnt(2)" ::: "memory");
        else      asm volatile("s_waitcnt vmcnt(0)" ::: "memory");
        __builtin_amdgcn_s_barrier();
        __builtin_amdgcn_sched_barrier(0);
        cur = cur == 2 ? 0 : cur + 1;
        sb  = sb  == 2 ? 0 : sb  + 1;
    }
#undef STAGE

#pragma unroll
    for (int i = 0; i < 4; ++i) {
#pragma unroll
        for (int j = 0; j < 2; ++j) {
            const int rr0 = row0 + wr * 64 + i * 16 + g * 4;  // C/D row=(l>>4)*4+r
            const int cc  = col0 + wc * 32 + j * 16 + qr;     //     col=l&15
            if (EPI == 4) {
                if (cc < 1024) {                 // q
#pragma unroll
                    for (int r = 0; r < 4; ++r)
                        ((bf16*)Cout)[(size_t)(rr0 + r) * 1024 + cc] = (bf16)acc[i][j][r];
                } else if (cc < 1536) {          // k
#pragma unroll
                    for (int r = 0; r < 4; ++r)
                        ((bf16*)res)[(size_t)(rr0 + r) * 512 + (cc - 1024)] = (bf16)acc[i][j][r];
                } else {                         // v transposed: Vt[b][kvh][d][s]
                    const int kv = cc - 1536, kvh = kv >> 6, d = kv & 63;
                    const int bb = rr0 >> 11, s0 = rr0 & 2047;
                    bf16 tmp[4];
#pragma unroll
                    for (int r = 0; r < 4; ++r) tmp[r] = (bf16)acc[i][j][r];
                    *(s16x4*)((bf16*)scale + (((size_t)bb * 8 + kvh) * 64 + d) * 2048 + s0) = *(s16x4*)tmp;
                }
            } else {
                float scv = 0.f;
                if (EPI == 1)
                    scv = f32 ? ((const float*)scale)[cc] : (float)((const bf16*)scale)[cc];
#pragma unroll
                for (int r = 0; r < 4; ++r) {
                    const size_t idx = (size_t)(rr0 + r) * N + cc;
                    float vv = acc[i][j][r];
                    if (EPI == 1) {
                        const float rv = (res_flv && f32) ? ((const float*)res)[idx]
                                                          : (float)((const bf16*)res)[idx];
                        vv = rv + vv * scv;
                    }
                    if (EPI == 3) {
                        const float uv = (float)((const bf16*)res)[idx];
                        vv = uv / (1.f + __expf(-uv)) * vv;
                    }
                    if (out_flv && f32) ((float*)Cout)[idx] = vv;
                    else                ((bf16*)Cout)[idx] = (bf16)vv;
                }
            }
        }
    }
}

// ---------------------------------------------------------------------------
// Windowed-ALiBi GQA flash attention (key in [q, q+512]).  Grid (S/64, H, B),
// 4 independent waves/block, wave = 16 queries.  Swapped QK^T (S^T=mfma(K,Q))
// so softmax state is lane-local; PV B-operand (P^T) built via __shfl.
// ---------------------------------------------------------------------------
__global__ __launch_bounds__(256)
void attn_kernel(const bf16* __restrict__ qn, const bf16* __restrict__ kn,
                 const bf16* __restrict__ vt, bf16* __restrict__ aout) {
    const int t = threadIdx.x, wv = t >> 6, ln = t & 63;
    const int qr = ln & 15, g = ln >> 4;
    const int h = blockIdx.y, b = blockIdx.z, kvh = h >> 1;
    const int q0w = blockIdx.x * 64 + wv * 16;
    const int qa = q0w + qr;
    const float slope = exp2f(-0.5f * (float)(h + 1));

    const bf16* qrow = qn + ((size_t)(b * 2048 + qa)) * 1024 + h * 64;
    const bf16x8 qb0 = *(const bf16x8*)(qrow + g * 8);
    const bf16x8 qb1 = *(const bf16x8*)(qrow + 32 + g * 8);

    const bf16* kbase = kn + (size_t)b * 2048 * 512 + kvh * 64;
    const bf16* vbase = vt + ((size_t)(b * 8 + kvh) * 64) * 2048;

    f32x4 o[4] = {};
    float mrun = -1e29f, lsum = 0.f;

    for (int kt = q0w; kt < q0w + 528; kt += 32) {
        f32x4 sc[2] = {f32x4{0, 0, 0, 0}, f32x4{0, 0, 0, 0}};
#pragma unroll
        for (int kf = 0; kf < 2; ++kf) {
            int krow = kt + kf * 16 + qr;
            krow = krow > 2047 ? 2047 : krow;
            const bf16* kr = kbase + (size_t)krow * 512;
            sc[kf] = MFMA16(*(const bf16x8*)(kr + g * 8),      qb0, sc[kf]);
            sc[kf] = MFMA16(*(const bf16x8*)(kr + 32 + g * 8), qb1, sc[kf]);
        }
        float s[2][4], p[2][4];
        float tmax = -1e30f;
#pragma unroll
        for (int kf = 0; kf < 2; ++kf)
#pragma unroll
            for (int r = 0; r < 4; ++r) {
                const int key = kt + kf * 16 + g * 4 + r;
                const int dist = key - qa;
                const bool valid = (dist >= 0) && (dist <= 512) && (key < 2048);
                const float sv = valid ? sc[kf][r] * 0.125f - slope * (float)dist : -1e30f;
                s[kf][r] = sv;
                tmax = fmaxf(tmax, sv);
            }
        tmax = fmaxf(tmax, __shfl_xor(tmax, 16));
        tmax = fmaxf(tmax, __shfl_xor(tmax, 32));
        const float mnew = fmaxf(mrun, tmax);
        const float alpha = __expf(mrun - mnew);
        mrun = mnew;
        float ps = 0.f;
#pragma unroll
        for (int kf = 0; kf < 2; ++kf)
#pragma unroll
            for (int r = 0; r < 4; ++r) { p[kf][r] = __expf(s[kf][r] - mnew); ps += p[kf][r]; }
        lsum = lsum * alpha + ps;
#pragma unroll
        for (int fd = 0; fd < 4; ++fd) o[fd] *= alpha;

        bf16x8 pb;
#pragma unroll
        for (int j = 0; j < 8; ++j) {
            const int srcl = (((2 * g + (j >> 2)) & 3) << 4) | qr;
            const float v0 = __shfl(p[0][j & 3], srcl);
            const float v1 = __shfl(p[1][j & 3], srcl);
            pb[j] = (bf16)((g & 2) ? v1 : v0);
        }
#pragma unroll
        for (int fd = 0; fd < 4; ++fd) {
            int kbv = kt + g * 8;
            kbv = kbv > 2040 ? 2040 : kbv;
            const bf16x8 va = *(const bf16x8*)(vbase + (size_t)(fd * 16 + qr) * 2048 + kbv);
            o[fd] = MFMA16(va, pb, o[fd]);
        }
    }
    float lt = lsum + __shfl_xor(lsum, 16);
    lt += __shfl_xor(lt, 32);
    lt = fmaxf(lt, 1e-30f);
    const float inv = 1.f / lt;
    bf16* orow = aout + ((size_t)(b * 2048 + qa)) * 1024 + h * 64;
#pragma unroll
    for (int fd = 0; fd < 4; ++fd) {
        bf16 tmp[4];
#pragma unroll
        for (int r = 0; r < 4; ++r) tmp[r] = (bf16)(o[fd][r] * inv);
        *(s16x4*)(orow + fd * 16 + g * 4) = *(s16x4*)tmp;
    }
}

// ---------------------------------------------------------------------------
extern "C" void kernel_launch(void* const* d_in, const int* in_sizes, int n_in,
                              void* d_out, int out_size, void* d_ws, size_t ws_size,
                              hipStream_t stream) {
    int* flag = (int*)d_ws;
    bf16* base = (bf16*)d_ws + 64;
    bf16* h    = base;                // 4096*1024  (reused as h2)
    bf16* q    = h + 4194304;         // 4096*1024  (reused as x1 after attn)
    bf16* kbuf = q + 4194304;         // 4096*512
    bf16* vtb  = kbuf + 2097152;      // 2*8*64*2048
    bf16* aout = vtb + 2097152;       // 4096*1024
    bf16* u    = aout + 4194304;      // 4096*4096  (reused as act)
    bf16* wcv  = u + 16777216;        // 15728640 converted weights (contiguous)

    bf16* woc = wcv + 2097152;
    bf16* w1c = wcv + 3145728;
    bf16* w3c = wcv + 7340032;
    bf16* w2c = wcv + 11534336;

    const dim3 blk(512);
    sniff_kernel<<<1, 256, 0, stream>>>((const unsigned short*)d_in[0], flag);
    convert_all_kernel<<<15360, 256, 0, stream>>>(
        d_in[1], d_in[2], d_in[3], d_in[4], d_in[9], d_in[11], d_in[10], wcv, flag);

    ln_kernel<<<4096, 128, 0, stream>>>(d_in[0], d_in[7], h, 1024, 1e-5f, flag, 1, 1);
    // fused QKV: B = [wq;wk;wv] rows, N=2048.  EPI4: Cout=q, res=kbuf, scale=vtb
    gemm2<4><<<dim3(16, 32), blk, 0, stream>>>(h, wcv, q, kbuf, vtb, 4096, 2048, 1024, flag, 0, 0);
    ln_kernel<<<4096, 128, 0, stream>>>(q, d_in[5], q, 1024, 1e-6f, flag, 0, 1);
    ln_kernel<<<4096, 128, 0, stream>>>(kbuf, d_in[6], kbuf, 512, 1e-6f, flag, 0, 1);
    attn_kernel<<<dim3(32, 16, 2), dim3(256), 0, stream>>>(q, kbuf, vtb, aout);
    // x1 = x + (aout@wo^T)*attn_scale  -> q (bf16)
    gemm2<1><<<dim3(8, 32), blk, 0, stream>>>(aout, woc, q, d_in[0], d_in[12], 4096, 1024, 1024, flag, 1, 0);
    ln_kernel<<<4096, 128, 0, stream>>>(q, d_in[8], h, 1024, 1e-5f, flag, 0, 1);
    gemm2<0><<<dim3(32, 32), blk, 0, stream>>>(h, w1c, u, nullptr, nullptr, 4096, 4096, 1024, flag, 0, 0);
    gemm2<3><<<dim3(32, 32), blk, 0, stream>>>(h, w3c, u, u, nullptr, 4096, 4096, 1024, flag, 0, 0);
    gemm2<1><<<dim3(8, 32), blk, 0, stream>>>(u, w2c, d_out, q, d_in[13], 4096, 1024, 4096, flag, 0, 1);
}